// Round 18
// baseline (32.479 us; speedup 1.0000x reference)
//
#include <hip/hip_runtime.h>
#include <math.h>

#define BATCH 4
#define NPTS  8192
#define TOTAL (BATCH * NPTS)            // 32768 points per set
#define TPB   256

#define CT     2                        // fixed col-tiles per wave (32 cols each)
#define WPB    (TPB / 64)               // 4 waves per block
#define COLS_PER_WAVE  (32 * CT)        // 64
#define COLS_PER_BLOCK (COLS_PER_WAVE * WPB)  // 256
#define ROWCH  16                       // swept-row chunks
#define SWEEP  (NPTS / ROWCH)           // 512 rows swept per wave
#define NT     (SWEEP / 32)             // 16 A-tiles per sweep

typedef __bf16 bf16v8 __attribute__((ext_vector_type(8)));
typedef float  f32x16 __attribute__((ext_vector_type(16)));

// ws layout:
//   Af: ushort[2*TOTAL*16] @ 0    (2 MB)  A-form K-vectors, set1 then set2
//   Bf: ushort[2*TOTAL*16] @ 2 MB (2 MB)  B-form K-vectors, set1 then set2
//   minbuf: uint[2*TOTAL]  @ 4 MB (256 KB) dist1 then dist2

__device__ __forceinline__ unsigned f2ord(float f) {
  unsigned b = __float_as_uint(f);
  return ((int)b >= 0) ? (b ^ 0x80000000u) : ~b;
}
__device__ __forceinline__ float ord2f(unsigned k) {
  unsigned b = (k & 0x80000000u) ? (k ^ 0x80000000u) : ~k;
  return __uint_as_float(b);
}
__device__ __forceinline__ unsigned short f2bf(float f) {   // RNE
  unsigned u = __float_as_uint(f);
  return (unsigned short)((u + 0x7fffu + ((u >> 16) & 1u)) >> 16);
}
__device__ __forceinline__ float bf2f(unsigned short h) {
  return __uint_as_float(((unsigned)h) << 16);
}
// min3-shaped fminf nesting (ISel fuses to v_min3_f32)
__device__ __forceinline__ float mf3(float a, float b, float c) {
  return fminf(fminf(a, b), c);
}
// min over 16 acc elements folded with carry-in (8 x v_min3)
__device__ __forceinline__ float coltree(const f32x16& a, float colt) {
  float t0 = mf3(a[0], a[1], a[2]);
  float t1 = mf3(a[3], a[4], a[5]);
  float t2 = mf3(a[6], a[7], a[8]);
  float t3 = mf3(a[9], a[10], a[11]);
  float t4 = mf3(a[12], a[13], a[14]);
  return mf3(colt, mf3(t0, t1, a[15]), mf3(t2, t3, t4));
}

// K-slot pairing (A[k]*B[k]), verified absmax 0 since R4:
//  k0-2: ah*ch   k3-5: al*ch   k6-8: ah*cl   (c = -2b)
//  k9,10: sq_a{h,l} * 1,1      k11,12: 1,1 * sq_b{h,l}     k13-15: 0
__global__ __launch_bounds__(TPB) void pack_kernel(
    const float* __restrict__ x1, const float* __restrict__ x2,
    unsigned short* __restrict__ Af, unsigned short* __restrict__ Bf,
    unsigned* __restrict__ minbuf, float* __restrict__ out) {
  int i = blockIdx.x * TPB + threadIdx.x;   // 0 .. 2*TOTAL-1  (set-major)
  if (i == 0) out[0] = 0.0f;
  minbuf[i] = 0xFFFFFFFFu;

  bool s2 = (i >= TOTAL);
  int j = s2 ? i - TOTAL : i;
  const float* src = s2 ? x2 : x1;
  float x = src[3 * j + 0];
  float y = src[3 * j + 1];
  float z = src[3 * j + 2];
  float sq = fmaf(x, x, fmaf(y, y, z * z));
  unsigned short sh = f2bf(sq);
  unsigned short sl = f2bf(sq - bf2f(sh));
  const unsigned short one = 0x3F80;

  unsigned short hx = f2bf(x), hy = f2bf(y), hz = f2bf(z);
  unsigned short lx = f2bf(x - bf2f(hx)), ly = f2bf(y - bf2f(hy)), lz = f2bf(z - bf2f(hz));
  float cx = -2.0f * x, cy = -2.0f * y, cz = -2.0f * z;
  unsigned short chx = f2bf(cx), chy = f2bf(cy), chz = f2bf(cz);
  unsigned short clx = f2bf(cx - bf2f(chx)), cly = f2bf(cy - bf2f(chy)), clz = f2bf(cz - bf2f(chz));

  // A-form
  {
    unsigned short v[16] = {hx, hy, hz, lx, ly, lz, hx, hy, hz,
                            sh, sl, one, one, 0, 0, 0};
    uint4* dst = (uint4*)(Af + (size_t)i * 16);
    uint4 w0, w1;
    w0.x = v[0] | ((unsigned)v[1] << 16);  w0.y = v[2] | ((unsigned)v[3] << 16);
    w0.z = v[4] | ((unsigned)v[5] << 16);  w0.w = v[6] | ((unsigned)v[7] << 16);
    w1.x = v[8] | ((unsigned)v[9] << 16);  w1.y = v[10] | ((unsigned)v[11] << 16);
    w1.z = v[12] | ((unsigned)v[13] << 16); w1.w = v[14] | ((unsigned)v[15] << 16);
    dst[0] = w0; dst[1] = w1;
  }
  // B-form
  {
    unsigned short v[16] = {chx, chy, chz, chx, chy, chz, clx, cly, clz,
                            one, one, sh, sl, 0, 0, 0};
    uint4* dst = (uint4*)(Bf + (size_t)i * 16);
    uint4 w0, w1;
    w0.x = v[0] | ((unsigned)v[1] << 16);  w0.y = v[2] | ((unsigned)v[3] << 16);
    w0.z = v[4] | ((unsigned)v[5] << 16);  w0.w = v[6] | ((unsigned)v[7] << 16);
    w1.x = v[8] | ((unsigned)v[9] << 16);  w1.y = v[10] | ((unsigned)v[11] << 16);
    w1.z = v[12] | ((unsigned)v[13] << 16); w1.w = v[14] | ((unsigned)v[15] << 16);
    dst[0] = w0; dst[1] = w1;
  }
}

// Col-min-only pass, both directions via blockIdx.z. R18 = R15 champion
// with REGISTER-ECONOMY delta targeting zc rematerialization: (1) pin the
// zero C-operand live in arch-VGPRs once (asm "+v"), (2) unroll 4x4 so
// only 4 A-loads are staged (16 regs, offsets 0/1024/2048/3072 all fold
// into immediate offset: fields -> near-zero address VALU) and the
// allocator has no pressure reason to re-zero 16 regs per MFMA.
__global__ __launch_bounds__(TPB, 4) void min_kernel(
    const unsigned short* __restrict__ Af, const unsigned short* __restrict__ Bf,
    unsigned* __restrict__ minbuf) {
  const int z   = blockIdx.z;
  const int b   = z & (BATCH - 1);
  const int dir = z >> 2;
  const int tid = threadIdx.x;
  const int wave = tid >> 6, lane = tid & 63;
  const int g = lane >> 5, l31 = lane & 31;

  const int colset = dir * TOTAL;          // offset of the col (target) set
  const int rowset = TOTAL - colset;       // offset of the swept set
  const int colbase = blockIdx.x * COLS_PER_BLOCK + wave * COLS_PER_WAVE;
  const int rowbase = blockIdx.y * SWEEP;

  // fixed B fragments: CT=2 col-tiles
  const bf16v8* bv = (const bf16v8*)Bf;
  bf16v8 bfr0 = bv[(size_t)(colset + b * NPTS + colbase + l31) * 2 + g];
  bf16v8 bfr1 = bv[(size_t)(colset + b * NPTS + colbase + 32 + l31) * 2 + g];

  f32x16 zc;
#pragma unroll
  for (int q = 0; q < 16; ++q) zc[q] = 0.0f;
  asm("" : "+v"(zc));   // force zc materialized ONCE in arch-VGPRs (no remat)

  float colacc0 = INFINITY, colacc1 = INFINITY;

  const bf16v8* bp = (const bf16v8*)Af + (size_t)(rowset + b * NPTS + rowbase + l31) * 2 + g;

  for (int c = 0; c < NT / 4; ++c) {       // 4 chunks
#pragma unroll
    for (int t = 0; t < 4; ++t) {          // 4 tiles/chunk, imm-offset loads
      bf16v8 a = bp[t * 64];
      f32x16 acc0 = __builtin_amdgcn_mfma_f32_32x32x16_bf16(a, bfr0, zc, 0, 0, 0);
      f32x16 acc1 = __builtin_amdgcn_mfma_f32_32x32x16_bf16(a, bfr1, zc, 0, 0, 0);
      colacc0 = coltree(acc0, colacc0);
      colacc1 = coltree(acc1, colacc1);
    }
    bp += 256;
  }

  // tail: merge g-halves (rows split across lane>>5), one masked atomic per tile
  {
    float m0 = fminf(colacc0, __shfl_xor(colacc0, 32));
    float m1 = fminf(colacc1, __shfl_xor(colacc1, 32));
    if (g == 0) {
      atomicMin(&minbuf[colset + b * NPTS + colbase + l31], f2ord(m0));
      atomicMin(&minbuf[colset + b * NPTS + colbase + 32 + l31], f2ord(m1));
    }
  }
}

__global__ __launch_bounds__(TPB) void finalize_kernel(
    const unsigned* __restrict__ minbuf, float* __restrict__ out, float scale) {
  int idx = blockIdx.x * TPB + threadIdx.x;   // 0 .. 2*TOTAL-1
  float v = ord2f(minbuf[idx]) * scale;
  for (int off = 32; off > 0; off >>= 1) v += __shfl_down(v, off);
  __shared__ float ls[TPB / 64];
  if ((threadIdx.x & 63) == 0) ls[threadIdx.x >> 6] = v;
  __syncthreads();
  if (threadIdx.x == 0) {
    float t = 0.0f;
#pragma unroll
    for (int w = 0; w < TPB / 64; ++w) t += ls[w];
    atomicAdd(out, t);
  }
}

extern "C" void kernel_launch(void* const* d_in, const int* in_sizes, int n_in,
                              void* d_out, int out_size, void* d_ws, size_t ws_size,
                              hipStream_t stream) {
  const float* xyz1 = (const float*)d_in[0];
  const float* xyz2 = (const float*)d_in[1];
  float* out = (float*)d_out;

  char* ws = (char*)d_ws;
  unsigned short* Af = (unsigned short*)(ws);
  unsigned short* Bf = (unsigned short*)(ws + (size_t)2 * TOTAL * 32);
  unsigned*   minbuf = (unsigned*)(ws + (size_t)4 * TOTAL * 32);

  // 1) pack A/B forms for both sets + init minbuf + zero out
  pack_kernel<<<dim3(2 * TOTAL / TPB), dim3(TPB), 0, stream>>>(
      xyz1, xyz2, Af, Bf, minbuf, out);

  // 2) both directions, col-min only: 32 x 16 x 8 = 4096 blocks
  dim3 mgrid(NPTS / COLS_PER_BLOCK, ROWCH, 2 * BATCH);
  min_kernel<<<mgrid, dim3(TPB), 0, stream>>>(Af, Bf, minbuf);

  // 3) finalize: mean(dist1) + mean(dist2)
  const float scale = 1.0f / (float)TOTAL;
  finalize_kernel<<<dim3(2 * TOTAL / TPB), dim3(TPB), 0, stream>>>(minbuf, out, scale);
}

// Round 20
// 30.633 us; speedup vs baseline: 1.0603x; 1.0603x over previous
//
#include <hip/hip_runtime.h>
#include <math.h>

#define BATCH 4
#define NPTS  8192
#define TOTAL (BATCH * NPTS)            // 32768 points per set
#define TPB   256

#define CT     2                        // fixed col-tiles per wave (32 cols each)
#define WPB    (TPB / 64)               // 4 waves per block
#define COLS_PER_WAVE  (32 * CT)        // 64
#define COLS_PER_BLOCK (COLS_PER_WAVE * WPB)  // 256
#define ROWCH  16                       // swept-row chunks
#define SWEEP  (NPTS / ROWCH)           // 512 rows swept per wave
#define NT     (SWEEP / 32)             // 16 A-tiles per sweep

typedef __bf16 bf16v8 __attribute__((ext_vector_type(8)));
typedef float  f32x16 __attribute__((ext_vector_type(16)));

// ws layout (TILE-MAJOR, MFMA-LANE-ORDER packing, stride FIXED vs R19):
//   One tile = 32 points = 64 lane-fragments x 16B = 1KB = 512 ushorts.
//   Af: ushort[2*TOTAL*16] @ 0    (2 MB)  tile t at [t*512, t*512+512);
//        ushort t*512 + l*8 = fragment of lane l (point t*32+(l&31),
//        K-group l>>5). Wave load = tilebase + lane*16B, contiguous 1KB.
//   Bf: ushort[2*TOTAL*16] @ 2 MB (2 MB)  same layout
//   minbuf: uint[2*TOTAL]  @ 4 MB (256 KB) dist1 then dist2
//   Bounds: max tile index 2047 -> last ushort = 2047*512+511 = 2MB-1. Exact.

__device__ __forceinline__ unsigned f2ord(float f) {
  unsigned b = __float_as_uint(f);
  return ((int)b >= 0) ? (b ^ 0x80000000u) : ~b;
}
__device__ __forceinline__ float ord2f(unsigned k) {
  unsigned b = (k & 0x80000000u) ? (k ^ 0x80000000u) : ~k;
  return __uint_as_float(b);
}
__device__ __forceinline__ unsigned short f2bf(float f) {   // RNE
  unsigned u = __float_as_uint(f);
  return (unsigned short)((u + 0x7fffu + ((u >> 16) & 1u)) >> 16);
}
__device__ __forceinline__ float bf2f(unsigned short h) {
  return __uint_as_float(((unsigned)h) << 16);
}
// min3-shaped fminf nesting (ISel fuses to v_min3_f32)
__device__ __forceinline__ float mf3(float a, float b, float c) {
  return fminf(fminf(a, b), c);
}
// min over 16 acc elements folded with carry-in (8 x v_min3)
__device__ __forceinline__ float coltree(const f32x16& a, float colt) {
  float t0 = mf3(a[0], a[1], a[2]);
  float t1 = mf3(a[3], a[4], a[5]);
  float t2 = mf3(a[6], a[7], a[8]);
  float t3 = mf3(a[9], a[10], a[11]);
  float t4 = mf3(a[12], a[13], a[14]);
  return mf3(colt, mf3(t0, t1, a[15]), mf3(t2, t3, t4));
}

// K-slot pairing (A[k]*B[k]), verified absmax 0 since R4:
//  k0-2: ah*ch   k3-5: al*ch   k6-8: ah*cl   (c = -2b)
//  k9,10: sq_a{h,l} * 1,1      k11,12: 1,1 * sq_b{h,l}     k13-15: 0
__global__ __launch_bounds__(TPB) void pack_kernel(
    const float* __restrict__ x1, const float* __restrict__ x2,
    unsigned short* __restrict__ Af, unsigned short* __restrict__ Bf,
    unsigned* __restrict__ minbuf, float* __restrict__ out) {
  int i = blockIdx.x * TPB + threadIdx.x;   // 0 .. 2*TOTAL-1  (set-major)
  if (i == 0) out[0] = 0.0f;
  minbuf[i] = 0xFFFFFFFFu;

  bool s2 = (i >= TOTAL);
  int j = s2 ? i - TOTAL : i;
  const float* src = s2 ? x2 : x1;
  float x = src[3 * j + 0];
  float y = src[3 * j + 1];
  float z = src[3 * j + 2];
  float sq = fmaf(x, x, fmaf(y, y, z * z));
  unsigned short sh = f2bf(sq);
  unsigned short sl = f2bf(sq - bf2f(sh));
  const unsigned short one = 0x3F80;

  unsigned short hx = f2bf(x), hy = f2bf(y), hz = f2bf(z);
  unsigned short lx = f2bf(x - bf2f(hx)), ly = f2bf(y - bf2f(hy)), lz = f2bf(z - bf2f(hz));
  float cx = -2.0f * x, cy = -2.0f * y, cz = -2.0f * z;
  unsigned short chx = f2bf(cx), chy = f2bf(cy), chz = f2bf(cz);
  unsigned short clx = f2bf(cx - bf2f(chx)), cly = f2bf(cy - bf2f(chy)), clz = f2bf(cz - bf2f(chz));

  // tile-major lane-order store offsets (ushort units), tile stride 512:
  //   group0 frag -> (i>>5)*512 +   0 + (i&31)*8
  //   group1 frag -> (i>>5)*512 + 256 + (i&31)*8
  size_t o0 = (size_t)(i >> 5) * 512 + (size_t)(i & 31) * 8;
  size_t o1 = o0 + 256;

  // A-form
  {
    unsigned short v[16] = {hx, hy, hz, lx, ly, lz, hx, hy, hz,
                            sh, sl, one, one, 0, 0, 0};
    uint4 w0, w1;
    w0.x = v[0] | ((unsigned)v[1] << 16);  w0.y = v[2] | ((unsigned)v[3] << 16);
    w0.z = v[4] | ((unsigned)v[5] << 16);  w0.w = v[6] | ((unsigned)v[7] << 16);
    w1.x = v[8] | ((unsigned)v[9] << 16);  w1.y = v[10] | ((unsigned)v[11] << 16);
    w1.z = v[12] | ((unsigned)v[13] << 16); w1.w = v[14] | ((unsigned)v[15] << 16);
    *(uint4*)(Af + o0) = w0;
    *(uint4*)(Af + o1) = w1;
  }
  // B-form
  {
    unsigned short v[16] = {chx, chy, chz, chx, chy, chz, clx, cly, clz,
                            one, one, sh, sl, 0, 0, 0};
    uint4 w0, w1;
    w0.x = v[0] | ((unsigned)v[1] << 16);  w0.y = v[2] | ((unsigned)v[3] << 16);
    w0.z = v[4] | ((unsigned)v[5] << 16);  w0.w = v[6] | ((unsigned)v[7] << 16);
    w1.x = v[8] | ((unsigned)v[9] << 16);  w1.y = v[10] | ((unsigned)v[11] << 16);
    w1.z = v[12] | ((unsigned)v[13] << 16); w1.w = v[14] | ((unsigned)v[15] << 16);
    *(uint4*)(Bf + o0) = w0;
    *(uint4*)(Bf + o1) = w1;
  }
}

// Col-min-only pass, both directions via blockIdx.z. R20 = R15 champion
// (cap (256,4), full unroll) + tile-major lane-order loads (stride-FIXED):
// every wave-load is `tilebase + lane*16B` -- one contiguous 1KB segment,
// zero swizzle address math.
__global__ __launch_bounds__(TPB, 4) void min_kernel(
    const unsigned short* __restrict__ Af, const unsigned short* __restrict__ Bf,
    unsigned* __restrict__ minbuf) {
  const int z   = blockIdx.z;
  const int b   = z & (BATCH - 1);
  const int dir = z >> 2;
  const int tid = threadIdx.x;
  const int wave = tid >> 6, lane = tid & 63;
  const int g = lane >> 5, l31 = lane & 31;

  const int colset = dir * TOTAL;          // offset of the col (target) set
  const int rowset = TOTAL - colset;       // offset of the swept set
  const int colbase = blockIdx.x * COLS_PER_BLOCK + wave * COLS_PER_WAVE;
  const int rowbase = blockIdx.y * SWEEP;

  // fixed B fragments: CT=2 col-tiles, lane-sequential loads (tile = 64 bf16v8)
  const int bt0 = (colset + b * NPTS + colbase) >> 5;   // tile index
  const bf16v8* bvt = (const bf16v8*)Bf;
  bf16v8 bfr0 = bvt[(size_t)bt0 * 64 + lane];
  bf16v8 bfr1 = bvt[(size_t)(bt0 + 1) * 64 + lane];

  f32x16 zc;
#pragma unroll
  for (int q = 0; q < 16; ++q) zc[q] = 0.0f;
  float colacc0 = INFINITY, colacc1 = INFINITY;

  const int at0 = (rowset + b * NPTS + rowbase) >> 5;   // first swept tile
  const bf16v8* ap = (const bf16v8*)Af + (size_t)at0 * 64 + lane;

#pragma unroll
  for (int ti = 0; ti < NT; ++ti) {
    bf16v8 a = ap[ti * 64];                // lane-sequential, 1KB contiguous
    f32x16 acc0 = __builtin_amdgcn_mfma_f32_32x32x16_bf16(a, bfr0, zc, 0, 0, 0);
    f32x16 acc1 = __builtin_amdgcn_mfma_f32_32x32x16_bf16(a, bfr1, zc, 0, 0, 0);
    colacc0 = coltree(acc0, colacc0);
    colacc1 = coltree(acc1, colacc1);
  }

  // tail: merge g-halves (rows split across lane>>5), one masked atomic per tile
  {
    float m0 = fminf(colacc0, __shfl_xor(colacc0, 32));
    float m1 = fminf(colacc1, __shfl_xor(colacc1, 32));
    if (g == 0) {
      atomicMin(&minbuf[colset + b * NPTS + colbase + l31], f2ord(m0));
      atomicMin(&minbuf[colset + b * NPTS + colbase + 32 + l31], f2ord(m1));
    }
  }
}

__global__ __launch_bounds__(TPB) void finalize_kernel(
    const unsigned* __restrict__ minbuf, float* __restrict__ out, float scale) {
  int idx = blockIdx.x * TPB + threadIdx.x;   // 0 .. 2*TOTAL-1
  float v = ord2f(minbuf[idx]) * scale;
  for (int off = 32; off > 0; off >>= 1) v += __shfl_down(v, off);
  __shared__ float ls[TPB / 64];
  if ((threadIdx.x & 63) == 0) ls[threadIdx.x >> 6] = v;
  __syncthreads();
  if (threadIdx.x == 0) {
    float t = 0.0f;
#pragma unroll
    for (int w = 0; w < TPB / 64; ++w) t += ls[w];
    atomicAdd(out, t);
  }
}

extern "C" void kernel_launch(void* const* d_in, const int* in_sizes, int n_in,
                              void* d_out, int out_size, void* d_ws, size_t ws_size,
                              hipStream_t stream) {
  const float* xyz1 = (const float*)d_in[0];
  const float* xyz2 = (const float*)d_in[1];
  float* out = (float*)d_out;

  char* ws = (char*)d_ws;
  unsigned short* Af = (unsigned short*)(ws);
  unsigned short* Bf = (unsigned short*)(ws + (size_t)2 * TOTAL * 32);
  unsigned*   minbuf = (unsigned*)(ws + (size_t)4 * TOTAL * 32);

  // 1) pack A/B forms for both sets (tile-major lane order) + init minbuf
  pack_kernel<<<dim3(2 * TOTAL / TPB), dim3(TPB), 0, stream>>>(
      xyz1, xyz2, Af, Bf, minbuf, out);

  // 2) both directions, col-min only: 32 x 16 x 8 = 4096 blocks
  dim3 mgrid(NPTS / COLS_PER_BLOCK, ROWCH, 2 * BATCH);
  min_kernel<<<mgrid, dim3(TPB), 0, stream>>>(Af, Bf, minbuf);

  // 3) finalize: mean(dist1) + mean(dist2)
  const float scale = 1.0f / (float)TOTAL;
  finalize_kernel<<<dim3(2 * TOTAL / TPB), dim3(TPB), 0, stream>>>(minbuf, out, scale);
}